// Round 14
// baseline (82.241 us; speedup 1.0000x reference)
//
#include <hip/hip_runtime.h>
#include <hip/hip_bf16.h>

// Problem: X[64][1024][128] fp32. out = mean_{b,s,t} (cos(x_bs, x_bt) - 1)^2
// Identity: sum_{s,t}(S_st-1)^2 = ||G||_F^2 - 2*||v||^2 + S^2,
//   G = Xn^T Xn (128x128 per batch), v = sum_s xn_s. 2.15 GFLOP, no SxS.
//
// ROUND-14: single variable vs round 13 (81.78 us): kA X-loads made
// lane-linear. Old mapping (t>>2 row, t&3 quarter) put wave lanes at 128-B
// stride -> 64 line-requests per load instr (one lane per 128-B line).
// New mapping g[k]=X4[k*256+t] -> each wave-instr reads 1 KB contiguous
// (8x fewer line requests; same class of fix as round 9's +16 us win).
// Row-norm reduce becomes width-32 shfl tree per k. kB/kF byte-identical.

#define BATCH 64
#define SEQ   1024
#define DIM   128

typedef float floatx4 __attribute__((ext_vector_type(4)));

#if defined(__has_builtin)
#if __has_builtin(__builtin_amdgcn_cvt_pk_fp8_f32)
#define HAVE_CVT_FP8 1
#endif
#endif

// manual OCP e4m3fn (RNE via add-carry trick, flush |x|<2^-6 to 0).
__device__ __forceinline__ unsigned f2e4m3(float x) {
    unsigned u = __builtin_bit_cast(unsigned, x);
    unsigned r = u + 0x7FFFFu + ((u >> 20) & 1u);   // RNE at mantissa bit 20
    unsigned t = (r >> 20) & 0x7FFu;                // E*8 | mant3
    unsigned mag = (t >= 968u) ? (t - 960u) : 0u;   // E>=121  <=>  e>=-6
    return mag | ((u >> 24) & 0x80u);
}

__device__ __forceinline__ unsigned pack4_fp8(const float* v) {
#ifdef HAVE_CVT_FP8
    int w = __builtin_amdgcn_cvt_pk_fp8_f32(v[0], v[1], 0, false);
    w = __builtin_amdgcn_cvt_pk_fp8_f32(v[2], v[3], w, true);
    return (unsigned)w;
#else
    return f2e4m3(v[0]) | (f2e4m3(v[1]) << 8) |
           (f2e4m3(v[2]) << 16) | (f2e4m3(v[3]) << 24);
#endif
}

// ws layout (bytes): [0,8MB) XnT tiled fp8; vpartA[1024][256] (1 MB); res[512].
#define XNT_B  0
#define VP_B   8388608
#define RES_B  (VP_B + 1024 * 256 * 4)

// tiled block: (rb=f/16, kk=s/32) -> 512 B at ((b*8+rb)*32+kk)<<9 bytes;
// within: uint2 index kqi*16 + l15 (lane-linear for kB: lane = kqi*16+l15).

// ---- kA: wg = chunk*64 + b (XCD b%8), chunk = 64 s-rows. Normalize (x16),
//      LDS-transpose, fp8-pack, tiled store + v partials (/16). ----
__global__ __launch_bounds__(256, 4)
void kA_norm_t(const float* __restrict__ X, unsigned* __restrict__ XnT,
               float* __restrict__ vpartA) {
    __shared__ __align__(16) float lds[64][132];   // 33.8 KB
    const int t     = threadIdx.x;
    const int wg    = blockIdx.x;          // chunk*64 + b
    const int b     = wg & 63, chunk = wg >> 6;
    const int f     = t & 127, sh = t >> 7;
    const int rb    = f >> 4, l15 = f & 15;
    const int rsub  = t >> 5;              // 0..7: this thread's row offset
    const int c4    = t & 31;              // float4 column within row

    // lane-linear loads: instr k reads float4 flat idx k*256+t -> 1 KB/wave
    const float4* X4 = (const float4*)(X + (size_t)(b * SEQ + chunk * 64) * DIM);
    float4 g[8];
#pragma unroll
    for (int k = 0; k < 8; ++k) g[k] = X4[k * 256 + t];

    // per k: this thread holds row r = 8k + rsub, cols c4*4..+3.
    // row-norm: width-32 shfl tree (row spans 32 consecutive lanes).
#pragma unroll
    for (int k = 0; k < 8; ++k) {
        float ssq = g[k].x * g[k].x + g[k].y * g[k].y +
                    g[k].z * g[k].z + g[k].w * g[k].w;
        ssq += __shfl_xor(ssq, 1);
        ssq += __shfl_xor(ssq, 2);
        ssq += __shfl_xor(ssq, 4);
        ssq += __shfl_xor(ssq, 8);
        ssq += __shfl_xor(ssq, 16);
        const float inv16 = rsqrtf(fmaxf(ssq, 1e-24f)) * 16.0f;  // scaled x16
        float4 n;
        n.x = g[k].x * inv16; n.y = g[k].y * inv16;
        n.z = g[k].z * inv16; n.w = g[k].w * inv16;
        *(float4*)&lds[8 * k + rsub][c4 * 4] = n;
    }
    __syncthreads();

    // transposed read: column f, rows sh*32..+31 (<=2-way banks: free)
    float vacc = 0.0f;
    float v[32];
#pragma unroll
    for (int j = 0; j < 32; ++j) {
        v[j] = lds[sh * 32 + j][f];
        vacc += v[j];
    }
    unsigned pk[8];
#pragma unroll
    for (int p = 0; p < 8; ++p) pk[p] = pack4_fp8(v + 4 * p);

    const int kk = chunk * 2 + sh;         // s-block of 32
    uint2* op = (uint2*)((char*)XnT +
                         ((size_t)((b * 8 + rb) * 32 + kk) << 9));
#pragma unroll
    for (int kqi = 0; kqi < 4; ++kqi)
        op[kqi * 16 + l15] = make_uint2(pk[2 * kqi], pk[2 * kqi + 1]);

    vpartA[(size_t)wg * 256 + t] = vacc * 0.0625f;   // undo x16
}

// ---- kB: wg = band*64 + b (XCD b%8). Full K=1024 Gram strip via fp8 MFMA,
//      lane-linear 512 B fragment loads; band 0 folds -2||v||^2. ----
__global__ __launch_bounds__(256, 2)
void kB_gram(const unsigned* __restrict__ XnT, const float* __restrict__ vpartA,
             float* __restrict__ res) {
    const int t    = threadIdx.x;
    const int wg   = blockIdx.x;
    const int b    = wg & 63, band = wg >> 6;
    const int lane = t & 63, w = t >> 6;

    const long* Ab  = (const long*)((const char*)XnT +
                      ((size_t)((b * 8 + band) * 32) << 9)) + lane;
    const long* B0b = (const long*)((const char*)XnT +
                      ((size_t)((b * 8 + 2 * w) * 32) << 9)) + lane;
    const long* B1b = (const long*)((const char*)XnT +
                      ((size_t)((b * 8 + 2 * w + 1) * 32) << 9)) + lane;

    floatx4 acc0 = {0.f, 0.f, 0.f, 0.f}, acc1 = {0.f, 0.f, 0.f, 0.f};
#pragma unroll 8
    for (int kk = 0; kk < 32; ++kk) {      // block stride = 512 B = 64 longs
        long a  = Ab[kk * 64];
        long b0 = B0b[kk * 64];
        long b1 = B1b[kk * 64];
        acc0 = __builtin_amdgcn_mfma_f32_16x16x32_fp8_fp8(a, b0, acc0, 0, 0, 0);
        acc1 = __builtin_amdgcn_mfma_f32_16x16x32_fp8_fp8(a, b1, acc1, 0, 0, 0);
    }

    float s = (acc0[0] * acc0[0] + acc0[1] * acc0[1] +
               acc0[2] * acc0[2] + acc0[3] * acc0[3] +
               acc1[0] * acc1[0] + acc1[1] * acc1[1] +
               acc1[2] * acc1[2] + acc1[3] * acc1[3]) * (1.0f / 65536.0f);

    if (band == 0 && t < DIM) {            // fold -2*||v_b||^2 (fp32 path)
        float vv = 0.0f;
#pragma unroll
        for (int c = 0; c < 16; ++c) {
            const float* p = vpartA + (size_t)(c * 64 + b) * 256;
            vv += p[t] + p[t + 128];
        }
        s -= 2.0f * vv * vv;
    }

#pragma unroll
    for (int m = 1; m < 64; m <<= 1) s += __shfl_xor(s, m);
    __shared__ float wq[4];
    if (lane == 0) wq[w] = s;
    __syncthreads();
    if (t == 0) res[wg] = wq[0] + wq[1] + wq[2] + wq[3];
}

// ---- kF: out = sum(res[0..511]) / (B*S^2) + 1 ----
__global__ __launch_bounds__(256)
void kF_final(const float* __restrict__ res, float* __restrict__ out) {
    const int t = threadIdx.x;
    float s = res[t] + res[t + 256];
#pragma unroll
    for (int m = 1; m < 64; m <<= 1) s += __shfl_xor(s, m);
    __shared__ float wq[4];
    if ((t & 63) == 0) wq[t >> 6] = s;
    __syncthreads();
    if (t == 0)
        out[0] = (wq[0] + wq[1] + wq[2] + wq[3]) * (1.0f / 67108864.0f) + 1.0f;
}

extern "C" void kernel_launch(void* const* d_in, const int* in_sizes, int n_in,
                              void* d_out, int out_size, void* d_ws, size_t ws_size,
                              hipStream_t stream) {
    const float* X = (const float*)d_in[0];
    char* ws = (char*)d_ws;                 // needs ~9.4 MB
    unsigned* XnT  = (unsigned*)(ws + XNT_B);
    float* vpartA  = (float*)(ws + VP_B);
    float* res     = (float*)(ws + RES_B);

    kA_norm_t<<<1024, 256, 0, stream>>>(X, XnT, vpartA);
    kB_gram<<<512, 256, 0, stream>>>(XnT, vpartA, res);
    kF_final<<<1, 256, 0, stream>>>(res, (float*)d_out);
}